// Round 1
// baseline (79941.626 us; speedup 1.0000x reference)
//
#include <hip/hip_runtime.h>
#include <cstdint>
#include <cstddef>

#define UU 1024
#define FOURU 4096
#define BATCH 64
#define TTT 128
#define SSS 16

typedef __attribute__((ext_vector_type(8))) short short8;
typedef __attribute__((ext_vector_type(4))) float f32x4;

__device__ __forceinline__ unsigned short f2bf(float f) {
    union { float f; uint32_t u; } v; v.f = f;
    uint32_t u = v.u;
    uint32_t r = (u + 0x7fffu + ((u >> 16) & 1u)) >> 16;
    return (unsigned short)r;
}
__device__ __forceinline__ float bf2f(unsigned short h) {
    union { uint32_t u; float f; } v; v.u = ((uint32_t)h) << 16;
    return v.f;
}

// ---------------------------------------------------------------------------
// Repack weights: original W[k][origcol] (f32, col-major over 4096 cols) ->
// packed [pc][K] bf16 hi/lo planes, where packed col pc = blk*16 + g*4 + j
// maps to origcol = g*1024 + blk*4 + j  (block blk owns units blk*4..blk*4+3).
// ---------------------------------------------------------------------------
__global__ void repack_w1(const float* __restrict__ r1,
                          unsigned short* __restrict__ whi,
                          unsigned short* __restrict__ wlo) {
    int idx = blockIdx.x * 256 + threadIdx.x;        // 4096*1024 elements
    int pc = idx >> 10, k = idx & 1023;
    int b = pc >> 4, g = (pc >> 2) & 3, j = pc & 3;
    int oc = g * UU + b * 4 + j;
    float v = r1[(size_t)k * FOURU + oc];
    unsigned short hi = f2bf(v);
    whi[idx] = hi;
    wlo[idx] = f2bf(v - bf2f(hi));
}

__global__ void repack_w2(const float* __restrict__ k2, const float* __restrict__ r2,
                          unsigned short* __restrict__ whi,
                          unsigned short* __restrict__ wlo) {
    int idx = blockIdx.x * 256 + threadIdx.x;        // 4096*2048 elements
    int pc = idx >> 11, k = idx & 2047;
    int b = pc >> 4, g = (pc >> 2) & 3, j = pc & 3;
    int oc = g * UU + b * 4 + j;
    float v = (k < UU) ? k2[(size_t)k * FOURU + oc]
                       : r2[(size_t)(k - UU) * FOURU + oc];
    unsigned short hi = f2bf(v);
    whi[idx] = hi;
    wlo[idx] = f2bf(v - bf2f(hi));
}

// ---------------------------------------------------------------------------
// One LSTM cell step. 256 blocks; block blk owns units blk*4..blk*4+3
// (16 z-columns across the 4 gates). 256 threads = 4 waves; wave w takes
// K-slice [w*KTOT/4, (w+1)*KTOT/4). A operand = h (and x for layer 2) as
// bf16 hi/lo planes; B operand = packed weights hi/lo. Split product:
// Whi*Ahi + Whi*Alo + Wlo*Ahi (3 MFMAs) ~ f32 precision.
// flags bit0: zero initial h (skip matmul / skip h-half). bit1: zero init c.
// ---------------------------------------------------------------------------
template <int KTOT, bool IS1>
__global__ __launch_bounds__(256, 1) void cell_step(
    const unsigned short* __restrict__ Whi, const unsigned short* __restrict__ Wlo,
    const unsigned short* __restrict__ A1hi, const unsigned short* __restrict__ A1lo,
    const unsigned short* __restrict__ A2hi, const unsigned short* __restrict__ A2lo,
    const float* __restrict__ cin, float* __restrict__ cout,
    unsigned short* __restrict__ Hhi, unsigned short* __restrict__ Hlo,
    const float* __restrict__ bias,
    const float* __restrict__ k1, const float* __restrict__ xsrc, int xstride,
    int flags) {
    __shared__ float zp[4][64][16];
    const int tid = threadIdx.x;
    const int lane = tid & 63;
    const int w = tid >> 6;
    const int blk = blockIdx.x;
    constexpr int KSL = KTOT / 4;

    f32x4 acc[4] = {};  // 4 M-tiles of 16 rows each (batch = 64)

    bool skip;
    if (IS1) skip = (flags & 1) != 0;
    else     skip = ((flags & 1) != 0) && (w >= 2);  // waves 2,3 cover k>=1024 (h half)

    if (!skip) {
        const int kbase = w * KSL;
        const unsigned short* Ah;
        const unsigned short* Al;
        int koff;
        if (KTOT == 2048 && kbase >= UU) { Ah = A2hi; Al = A2lo; koff = kbase - UU; }
        else                             { Ah = A1hi; Al = A1lo; koff = kbase; }
        const int kg8 = (lane >> 4) * 8;
        const int colpc = blk * 16 + (lane & 15);
        const unsigned short* wrh = Whi + (size_t)colpc * KTOT + kbase + kg8;
        const unsigned short* wrl = Wlo + (size_t)colpc * KTOT + kbase + kg8;

        for (int kk = 0; kk < KSL; kk += 32) {
            short8 bh = *(const short8*)(wrh + kk);
            short8 bl = *(const short8*)(wrl + kk);
#pragma unroll
            for (int m = 0; m < 4; ++m) {
                const int row = m * 16 + (lane & 15);
                const size_t aoff = (size_t)row * UU + koff + kk + kg8;
                short8 ah = *(const short8*)(Ah + aoff);
                short8 al = *(const short8*)(Al + aoff);
                acc[m] = __builtin_amdgcn_mfma_f32_16x16x32_bf16(ah, bh, acc[m], 0, 0, 0);
                acc[m] = __builtin_amdgcn_mfma_f32_16x16x32_bf16(al, bh, acc[m], 0, 0, 0);
                acc[m] = __builtin_amdgcn_mfma_f32_16x16x32_bf16(ah, bl, acc[m], 0, 0, 0);
            }
        }
    }

    // write partials: D layout col=lane&15, row=(lane>>4)*4+r  (m89-verified)
#pragma unroll
    for (int m = 0; m < 4; ++m) {
        const int rbase = m * 16 + (lane >> 4) * 4;
#pragma unroll
        for (int r = 0; r < 4; ++r)
            zp[w][rbase + r][lane & 15] = acc[m][r];
    }
    __syncthreads();

    // epilogue: 256 threads = 64 rows x 4 units
    {
        const int row = tid & 63;
        const int j = tid >> 6;
        float z[4];
#pragma unroll
        for (int g = 0; g < 4; ++g) {
            float s = 0.f;
#pragma unroll
            for (int ww = 0; ww < 4; ++ww) s += zp[ww][row][g * 4 + j];
            const int oc = g * UU + blk * 4 + j;
            s += bias[oc];
            if (IS1) {
                float xv = xsrc[(size_t)row * xstride];
                s += xv * k1[oc];
            }
            z[g] = s;
        }
        const int u = blk * 4 + j;
        float cold = (flags & 2) ? 0.f : cin[(size_t)row * UU + u];
        float ig = 1.f / (1.f + expf(-z[0]));
        float fg = 1.f / (1.f + expf(-z[1]));
        float gg = tanhf(z[2]);
        float og = 1.f / (1.f + expf(-z[3]));
        float cn = fg * cold + ig * gg;
        float hn = og * tanhf(cn);
        cout[(size_t)row * UU + u] = cn;
        unsigned short hh = f2bf(hn);
        Hhi[(size_t)row * UU + u] = hh;
        Hlo[(size_t)row * UU + u] = f2bf(hn - bf2f(hh));
    }
}

// ---------------------------------------------------------------------------
// Dense head: pred[b, t] = sum_u (X2hi+X2lo)[t][b][u] * wd[u] + bd.
// One wave per (t,b) dot product; 512 blocks x 256 thr = 2048 waves, 8192 dots.
// out points at d_out + s*T; final layout d_out[b*2048 + s*128 + t].
// ---------------------------------------------------------------------------
__global__ void dense_pred(const unsigned short* __restrict__ X2hi,
                           const unsigned short* __restrict__ X2lo,
                           const float* __restrict__ wd, const float* __restrict__ bd,
                           float* __restrict__ out) {
    const int gw = (blockIdx.x * 256 + threadIdx.x) >> 6;
    const int lane = threadIdx.x & 63;
    for (int d = gw; d < TTT * BATCH; d += 2048) {
        const int t = d >> 6, b = d & 63;
        const unsigned short* ph = X2hi + ((size_t)t * BATCH + b) * UU;
        const unsigned short* pl = X2lo + ((size_t)t * BATCH + b) * UU;
        float s = 0.f;
#pragma unroll 4
        for (int i = lane; i < UU; i += 64)
            s += (bf2f(ph[i]) + bf2f(pl[i])) * wd[i];
#pragma unroll
        for (int off = 32; off; off >>= 1) s += __shfl_down(s, off, 64);
        if (lane == 0) out[(size_t)b * (SSS * TTT) + t] = s + bd[0];
    }
}

// ---------------------------------------------------------------------------
extern "C" void kernel_launch(void* const* d_in, const int* in_sizes, int n_in,
                              void* d_out, int out_size, void* d_ws, size_t ws_size,
                              hipStream_t stream) {
    const float* inputs = (const float*)d_in[0];  // [64,128,1]
    const float* k1     = (const float*)d_in[1];  // [1,4096]
    const float* r1     = (const float*)d_in[2];  // [1024,4096]
    const float* b1     = (const float*)d_in[3];  // [4096]
    const float* k2     = (const float*)d_in[4];  // [1024,4096]
    const float* r2     = (const float*)d_in[5];  // [1024,4096]
    const float* b2     = (const float*)d_in[6];  // [4096]
    const float* wd     = (const float*)d_in[7];  // [1024,1]
    const float* bd     = (const float*)d_in[8];  // [1]
    float* out = (float*)d_out;                   // [64, 16*128, 1]

    char* ws = (char*)d_ws;
    size_t off = 0;
    auto carve = [&](size_t bytes) -> void* {
        void* p = ws + off;
        off += (bytes + 255) & ~(size_t)255;
        return p;
    };
    const size_t BU = (size_t)BATCH * UU;  // 65536 elems per (t) plane
    unsigned short* W1hi = (unsigned short*)carve((size_t)FOURU * UU * 2);
    unsigned short* W1lo = (unsigned short*)carve((size_t)FOURU * UU * 2);
    unsigned short* W2hi = (unsigned short*)carve((size_t)FOURU * 2048 * 2);
    unsigned short* W2lo = (unsigned short*)carve((size_t)FOURU * 2048 * 2);
    unsigned short* X1hi = (unsigned short*)carve((size_t)TTT * BU * 2);
    unsigned short* X1lo = (unsigned short*)carve((size_t)TTT * BU * 2);
    unsigned short* X2hi = (unsigned short*)carve((size_t)TTT * BU * 2);
    unsigned short* X2lo = (unsigned short*)carve((size_t)TTT * BU * 2);
    float* c1 = (float*)carve(BU * 4);
    float* c2 = (float*)carve(BU * 4);

    repack_w1<<<dim3((FOURU * UU) / 256), dim3(256), 0, stream>>>(r1, W1hi, W1lo);
    repack_w2<<<dim3((FOURU * 2048) / 256), dim3(256), 0, stream>>>(k2, r2, W2hi, W2lo);

    for (int s = 0; s < SSS; ++s) {
        // ---- LSTM1 scan (K=1024: recurrent only; rank-1 input term in epilogue)
        for (int t = 0; t < TTT; ++t) {
            const unsigned short *Ahi, *Alo;
            if (t == 0) { Ahi = X2hi + 127 * BU; Alo = X2lo + 127 * BU; }  // h2 final of s-1
            else        { Ahi = X1hi + (size_t)(t - 1) * BU; Alo = X1lo + (size_t)(t - 1) * BU; }
            const float* cinp = (t == 0) ? c2 : c1;
            int flags = (s == 0 && t == 0) ? 3 : 0;
            const float* xsrc;
            int xstride;
            if (s == 0) { xsrc = inputs + t; xstride = TTT; }
            else        { xsrc = out + (size_t)(s - 1) * TTT + t; xstride = SSS * TTT; }
            cell_step<1024, true><<<dim3(256), dim3(256), 0, stream>>>(
                W1hi, W1lo, Ahi, Alo, (const unsigned short*)nullptr, (const unsigned short*)nullptr,
                cinp, c1, X1hi + (size_t)t * BU, X1lo + (size_t)t * BU,
                b1, k1, xsrc, xstride, flags);
        }
        // ---- LSTM2 scan (K=2048: [x1_t ; h2_{t-1}] @ [k2 ; r2])
        for (int t = 0; t < TTT; ++t) {
            const unsigned short *A2hi_, *A2lo_;
            if (t == 0) { A2hi_ = X1hi + 127 * BU; A2lo_ = X1lo + 127 * BU; }  // h1 final of s
            else        { A2hi_ = X2hi + (size_t)(t - 1) * BU; A2lo_ = X2lo + (size_t)(t - 1) * BU; }
            const float* cinp = (t == 0) ? c1 : c2;
            int flags = (s == 0 && t == 0) ? 3 : 0;
            cell_step<2048, false><<<dim3(256), dim3(256), 0, stream>>>(
                W2hi, W2lo,
                X1hi + (size_t)t * BU, X1lo + (size_t)t * BU, A2hi_, A2lo_,
                cinp, c2, X2hi + (size_t)t * BU, X2lo + (size_t)t * BU,
                b2, (const float*)nullptr, (const float*)nullptr, 0, flags);
        }
        // ---- Dense head over the whole sequence; also feeds next outer step
        dense_pred<<<dim3(512), dim3(256), 0, stream>>>(X2hi, X2lo, wd, bd,
                                                        out + (size_t)s * TTT);
    }
}